// Round 4
// baseline (262.789 us; speedup 1.0000x reference)
//
#include <hip/hip_runtime.h>
#include <math.h>

// Problem constants
#define S_N 16
#define D_N 256
#define H_N 128
#define K_N 32
#define BT  64   // batch rows per workgroup

typedef __attribute__((ext_vector_type(8))) short bf16x8;
typedef __attribute__((ext_vector_type(4))) float f32x4;

#define MFMA(a, b, c) __builtin_amdgcn_mfma_f32_16x16x32_bf16(a, b, c, 0, 0, 0)

static __device__ __forceinline__ unsigned short f2bf(float f) {
  union { float f; unsigned u; } v; v.f = f;
  unsigned r = v.u + 0x7FFFu + ((v.u >> 16) & 1u);  // RNE
  return (unsigned short)(r >> 16);
}

// ---------------- weight cast + transpose pre-pass ----------------
__global__ __launch_bounds__(256)
void lsi_transpose(const float* __restrict__ W1, const float* __restrict__ W2,
                   const float* __restrict__ Wc1,
                   unsigned short* __restrict__ W1t,
                   unsigned short* __restrict__ W2t,
                   unsigned short* __restrict__ Wc1t)
{
  __shared__ float t[32][33];
  int bid = blockIdx.x;
  const float* src; unsigned short* dst; int R, C, r0, c0;
  if (bid < 512) {                       // W1: 16 s * (8x4) tiles
    int s = bid >> 5, tt = bid & 31;
    R = 256; C = 128; r0 = (tt >> 2) * 32; c0 = (tt & 3) * 32;
    src = W1 + (size_t)s * 256 * 128; dst = W1t + (size_t)s * 128 * 256;
  } else if (bid < 1024) {               // W2: 16 s * (4x8) tiles
    int s = (bid - 512) >> 5, tt = (bid - 512) & 31;
    R = 128; C = 256; r0 = (tt >> 3) * 32; c0 = (tt & 7) * 32;
    src = W2 + (size_t)s * 128 * 256; dst = W2t + (size_t)s * 256 * 128;
  } else {                               // Wc1: 16 s * (8x1) tiles
    int s = (bid - 1024) >> 3, tt = (bid - 1024) & 7;
    R = 256; C = 32; r0 = tt * 32; c0 = 0;
    src = Wc1 + (size_t)s * 256 * 32; dst = Wc1t + (size_t)s * 32 * 256;
  }
  int li = threadIdx.x >> 5, lj = threadIdx.x & 31;
  #pragma unroll
  for (int i = 0; i < 4; ++i)
    t[li + i * 8][lj] = src[(size_t)(r0 + li + i * 8) * C + c0 + lj];
  __syncthreads();
  #pragma unroll
  for (int i = 0; i < 4; ++i)
    dst[(size_t)(c0 + li + i * 8) * R + r0 + lj] = f2bf(t[lj][li + i * 8]);
}

// ---------------- fused main kernel ----------------
// grid = 256, block = 512 (8 waves). Sources processed in PAIRS (s, s2):
//   P1 (merged w/ prev accum): GEMM1(s)+GEMM1(s2) share x A-frags -> ha, hb
//   barA | P2: GEMM2(s) -> acc2 regs + o_lds          | barB
//   P3: GEMM3(s) -> shfl reduce -> zp_lds             | barC
//   P4: accum(s) (VALU) + GEMM2(s2) (MFMA/LDS) -> o   | barD
//   P5: GEMM3(s2) -> zp                               | barE
//   P6: accum(s2) + GEMM1 of next pair (pipe mixing)
// 5 barriers / 2 sources; no cross-phase register prefetch arrays.
__global__ __launch_bounds__(512, 2)
void lsi_main(const float* __restrict__ x,
              const float* __restrict__ b1,
              const float* __restrict__ b2,
              const float* __restrict__ bc1,
              const float* __restrict__ Wc2,
              const float* __restrict__ bc2,
              const float* __restrict__ lam,
              const unsigned short* __restrict__ W1t,
              const unsigned short* __restrict__ W2t,
              const unsigned short* __restrict__ Wc1t,
              float* __restrict__ out)
{
  __shared__ unsigned short x_lds[BT * D_N];    // 32 KB, swizzled
  __shared__ unsigned short ha_lds[BT * H_N];   // 16 KB, swizzled
  __shared__ unsigned short hb_lds[BT * H_N];   // 16 KB, swizzled
  __shared__ unsigned short o_lds[BT * D_N];    // 32 KB, swizzled
  __shared__ float zp_lds[2][BT];               // partial conf z

  const int tid = threadIdx.x;
  const int w   = tid >> 6;       // wave 0..7
  const int l   = tid & 63;       // lane
  const int rA  = l & 15;
  const int g   = l >> 4;         // k-group 0..3
  const int k8  = g * 8;
  const int b0  = blockIdx.x * BT;
  const int rt3 = w >> 1;         // GEMM3 row tile
  const int ct3 = w & 1;          // GEMM3 col tile

  // ---- stage x tile into LDS as bf16 (swizzled) ----
  {
    int row = tid >> 3;                 // 0..63
    int c0  = (tid & 7) * 32;           // 8 threads per row
    const float* xr = x + (size_t)(b0 + row) * D_N + c0;
    #pragma unroll
    for (int cc = 0; cc < 4; ++cc) {
      float4 f0 = *(const float4*)(xr + cc * 8);
      float4 f1 = *(const float4*)(xr + cc * 8 + 4);
      bf16x8 u;
      u[0] = f2bf(f0.x); u[1] = f2bf(f0.y); u[2] = f2bf(f0.z); u[3] = f2bf(f0.w);
      u[4] = f2bf(f1.x); u[5] = f2bf(f1.y); u[6] = f2bf(f1.z); u[7] = f2bf(f1.w);
      unsigned off = (unsigned)(row * 512 + (c0 + cc * 8) * 2) ^ (unsigned)((row & 7) << 4);
      *(bf16x8*)((char*)x_lds + off) = u;
    }
  }

  f32x4 out_acc[2][4];   // [ct][rt]
  f32x4 acc2[2][4];      // [ct][rt], current-source outs
  float wsum[4][4];      // [rt][i]
  #pragma unroll
  for (int a = 0; a < 2; ++a)
    #pragma unroll
    for (int b = 0; b < 4; ++b)
      out_acc[a][b] = (f32x4){0.f, 0.f, 0.f, 0.f};
  #pragma unroll
  for (int a = 0; a < 4; ++a)
    #pragma unroll
    for (int i = 0; i < 4; ++i)
      wsum[a][i] = 0.f;

  // ---- phase bodies ----
  auto gemm1_pair = [&](int s, int s2) {
    f32x4 a1a[4], a1b[4];
    #pragma unroll
    for (int rt = 0; rt < 4; ++rt) {
      a1a[rt] = (f32x4){0.f, 0.f, 0.f, 0.f};
      a1b[rt] = (f32x4){0.f, 0.f, 0.f, 0.f};
    }
    const unsigned short* B1a = W1t + ((size_t)s  * H_N + w * 16 + rA) * D_N + k8;
    const unsigned short* B1b = W1t + ((size_t)s2 * H_N + w * 16 + rA) * D_N + k8;
    #pragma unroll
    for (int ks = 0; ks < 8; ++ks) {
      bf16x8 bfa = *(const bf16x8*)(B1a + ks * 32);
      bf16x8 bfb = *(const bf16x8*)(B1b + ks * 32);
      #pragma unroll
      for (int rt = 0; rt < 4; ++rt) {
        int row = rt * 16 + rA;
        unsigned off = (unsigned)(row * 512 + (ks * 32 + k8) * 2) ^ (unsigned)((row & 7) << 4);
        bf16x8 afr = *(const bf16x8*)((const char*)x_lds + off);
        a1a[rt] = MFMA(afr, bfa, a1a[rt]);
        a1b[rt] = MFMA(afr, bfb, a1b[rt]);
      }
    }
    const float v1 = b1[s * H_N + w * 16 + rA];
    const float v2 = b1[s2 * H_N + w * 16 + rA];
    #pragma unroll
    for (int rt = 0; rt < 4; ++rt)
      #pragma unroll
      for (int i = 0; i < 4; ++i) {
        int row = rt * 16 + g * 4 + i;
        unsigned off = (unsigned)(row * 256 + (w * 16 + rA) * 2) ^ (unsigned)((row & 7) << 4);
        *(unsigned short*)((char*)ha_lds + off) = f2bf(fmaxf(a1a[rt][i] + v1, 0.f));
        *(unsigned short*)((char*)hb_lds + off) = f2bf(fmaxf(a1b[rt][i] + v2, 0.f));
      }
  };

  auto gemm2_phase = [&](int s, const unsigned short* hbuf) {
    #pragma unroll
    for (int a = 0; a < 2; ++a)
      #pragma unroll
      for (int b = 0; b < 4; ++b)
        acc2[a][b] = (f32x4){0.f, 0.f, 0.f, 0.f};
    const unsigned short* W2p = W2t + ((size_t)s * D_N + w * 32 + rA) * H_N + k8;
    #pragma unroll
    for (int ks = 0; ks < 4; ++ks) {
      bf16x8 afr[4];
      #pragma unroll
      for (int rt = 0; rt < 4; ++rt) {
        int row = rt * 16 + rA;
        unsigned off = (unsigned)(row * 256 + (ks * 32 + k8) * 2) ^ (unsigned)((row & 7) << 4);
        afr[rt] = *(const bf16x8*)((const char*)hbuf + off);
      }
      #pragma unroll
      for (int ct = 0; ct < 2; ++ct) {
        bf16x8 bfr = *(const bf16x8*)(W2p + ct * 16 * H_N + ks * 32);
        #pragma unroll
        for (int rt = 0; rt < 4; ++rt)
          acc2[ct][rt] = MFMA(afr[rt], bfr, acc2[ct][rt]);
      }
    }
    float b2v0 = b2[s * D_N + w * 32 + rA];
    float b2v1 = b2[s * D_N + w * 32 + 16 + rA];
    #pragma unroll
    for (int ct = 0; ct < 2; ++ct)
      #pragma unroll
      for (int rt = 0; rt < 4; ++rt)
        #pragma unroll
        for (int i = 0; i < 4; ++i) {
          float v = acc2[ct][rt][i] + (ct ? b2v1 : b2v0);
          acc2[ct][rt][i] = v;
          int row = rt * 16 + g * 4 + i;
          unsigned off = (unsigned)(row * 512 + (w * 32 + ct * 16 + rA) * 2) ^ (unsigned)((row & 7) << 4);
          *(unsigned short*)((char*)o_lds + off) = f2bf(v);
        }
  };

  auto gemm3_phase = [&](int s) {
    f32x4 acc3 = (f32x4){0.f, 0.f, 0.f, 0.f};
    const unsigned short* Wc1p = Wc1t + ((size_t)s * K_N + ct3 * 16 + rA) * D_N + k8;
    #pragma unroll
    for (int ks = 0; ks < 8; ++ks) {
      int row = rt3 * 16 + rA;
      unsigned off = (unsigned)(row * 512 + (ks * 32 + k8) * 2) ^ (unsigned)((row & 7) << 4);
      bf16x8 afr = *(const bf16x8*)((const char*)o_lds + off);
      bf16x8 bfr = *(const bf16x8*)(Wc1p + ks * 32);
      acc3 = MFMA(afr, bfr, acc3);
    }
    const float bc1v = bc1[s * K_N + ct3 * 16 + rA];
    const float wc2v = Wc2[s * K_N + ct3 * 16 + rA];
    float pz[4];
    #pragma unroll
    for (int i = 0; i < 4; ++i)
      pz[i] = fmaxf(acc3[i] + bc1v, 0.f) * wc2v;
    #pragma unroll
    for (int m = 1; m < 16; m <<= 1)
      #pragma unroll
      for (int i = 0; i < 4; ++i)
        pz[i] += __shfl_xor(pz[i], m);
    if (rA == 0) {
      #pragma unroll
      for (int i = 0; i < 4; ++i)
        zp_lds[ct3][rt3 * 16 + g * 4 + i] = pz[i];
    }
  };

  auto accum_phase = [&](int s) {
    const float lam_s = lam[s], bc2_s = bc2[s];
    #pragma unroll
    for (int rt = 0; rt < 4; ++rt)
      #pragma unroll
      for (int i = 0; i < 4; ++i) {
        int r = rt * 16 + g * 4 + i;
        float z  = zp_lds[0][r] + zp_lds[1][r] + bc2_s;
        float cw = lam_s / (1.f + __expf(-z));
        wsum[rt][i] += cw;
        #pragma unroll
        for (int ct = 0; ct < 2; ++ct)
          out_acc[ct][rt][i] += cw * acc2[ct][rt][i];
      }
  };

  __syncthreads();          // x staged
  gemm1_pair(0, 1);         // prologue P1

  for (int p = 0; p < 8; ++p) {
    const int s = 2 * p, s2 = 2 * p + 1;
    __syncthreads();                        // barA: ha/hb ready
    gemm2_phase(s, ha_lds);                 // P2
    __syncthreads();                        // barB: o(s) ready
    gemm3_phase(s);                         // P3
    __syncthreads();                        // barC: zp(s) ready
    accum_phase(s);                         // P4: VALU ...
    gemm2_phase(s2, hb_lds);                //      ... + MFMA/LDS mix
    __syncthreads();                        // barD: o(s2) ready
    gemm3_phase(s2);                        // P5
    __syncthreads();                        // barE: zp(s2) ready
    accum_phase(s2);                        // P6: VALU ...
    if (p < 7) gemm1_pair(s + 2, s + 3);    //      ... + MFMA/LDS mix
  }

  // ---------- finalize: out = out_acc / (wsum + 1e-6) ----------
  #pragma unroll
  for (int rt = 0; rt < 4; ++rt)
    #pragma unroll
    for (int i = 0; i < 4; ++i) {
      int r = rt * 16 + g * 4 + i;
      float winv = 1.f / (wsum[rt][i] + 1e-6f);
      #pragma unroll
      for (int ct = 0; ct < 2; ++ct)
        out[(size_t)(b0 + r) * D_N + w * 32 + ct * 16 + rA] = out_acc[ct][rt][i] * winv;
    }
}

extern "C" void kernel_launch(void* const* d_in, const int* in_sizes, int n_in,
                              void* d_out, int out_size, void* d_ws, size_t ws_size,
                              hipStream_t stream) {
  const float* x   = (const float*)d_in[0];
  const float* W1  = (const float*)d_in[1];
  const float* b1  = (const float*)d_in[2];
  const float* W2  = (const float*)d_in[3];
  const float* b2  = (const float*)d_in[4];
  const float* Wc1 = (const float*)d_in[5];
  const float* bc1 = (const float*)d_in[6];
  const float* Wc2 = (const float*)d_in[7];
  const float* bc2 = (const float*)d_in[8];
  const float* lam = (const float*)d_in[9];
  float* out = (float*)d_out;

  unsigned short* W1t  = (unsigned short*)d_ws;
  unsigned short* W2t  = W1t + (size_t)S_N * H_N * D_N;
  unsigned short* Wc1t = W2t + (size_t)S_N * D_N * H_N;

  hipLaunchKernelGGL(lsi_transpose, dim3(1152), dim3(256), 0, stream,
                     W1, W2, Wc1, W1t, W2t, Wc1t);
  hipLaunchKernelGGL(lsi_main, dim3(16384 / BT), dim3(512), 0, stream,
                     x, b1, b2, bc1, Wc2, bc2, lam, W1t, W2t, Wc1t, out);
}

// Round 5
// 132.465 us; speedup vs baseline: 1.9838x; 1.9838x over previous
//
#include <hip/hip_runtime.h>
#include <math.h>

// Problem constants
#define S_N 16
#define D_N 256
#define H_N 128
#define K_N 32
#define BT  64   // batch rows per workgroup

typedef __attribute__((ext_vector_type(8))) short bf16x8;
typedef __attribute__((ext_vector_type(4))) float f32x4;

#define MFMA(a, b, c) __builtin_amdgcn_mfma_f32_16x16x32_bf16(a, b, c, 0, 0, 0)

static __device__ __forceinline__ unsigned short f2bf(float f) {
  union { float f; unsigned u; } v; v.f = f;
  unsigned r = v.u + 0x7FFFu + ((v.u >> 16) & 1u);  // RNE
  return (unsigned short)(r >> 16);
}

// ---------------- weight cast + transpose pre-pass ----------------
// W1 [16][256][128] f32 -> W1t [16][128][256] bf16   (B of GEMM1, n-major)
// W2 [16][128][256] f32 -> W2t [16][256][128] bf16   (B of GEMM2, n-major)
__global__ __launch_bounds__(256)
void lsi_transpose(const float* __restrict__ W1, const float* __restrict__ W2,
                   unsigned short* __restrict__ W1t,
                   unsigned short* __restrict__ W2t)
{
  __shared__ float t[32][33];
  int bid = blockIdx.x;
  const float* src; unsigned short* dst; int R, C, r0, c0;
  if (bid < 512) {                       // W1: 16 s * (8x4) tiles
    int s = bid >> 5, tt = bid & 31;
    R = 256; C = 128; r0 = (tt >> 2) * 32; c0 = (tt & 3) * 32;
    src = W1 + (size_t)s * 256 * 128; dst = W1t + (size_t)s * 128 * 256;
  } else {                               // W2: 16 s * (4x8) tiles
    int s = (bid - 512) >> 5, tt = (bid - 512) & 31;
    R = 128; C = 256; r0 = (tt >> 3) * 32; c0 = (tt & 7) * 32;
    src = W2 + (size_t)s * 128 * 256; dst = W2t + (size_t)s * 256 * 128;
  }
  int li = threadIdx.x >> 5, lj = threadIdx.x & 31;
  #pragma unroll
  for (int i = 0; i < 4; ++i)
    t[li + i * 8][lj] = src[(size_t)(r0 + li + i * 8) * C + c0 + lj];
  __syncthreads();
  #pragma unroll
  for (int i = 0; i < 4; ++i)
    dst[(size_t)(c0 + li + i * 8) * R + r0 + lj] = f2bf(t[lj][li + i * 8]);
}

// ---------------- fused-weight pre-pass ----------------
// Wf[s]  = W2[s] (128x256) . Wc1[s] (256x32)  -> [128][32]
// stored n-major: Wft[s][k=32][hh=128] bf16
// bcf[s][k] = sum_d b2[s][d]*Wc1[s][d][k] + bc1[s][k]   (f32)
__global__ __launch_bounds__(256)
void lsi_wfuse(const float* __restrict__ W2, const float* __restrict__ Wc1,
               const float* __restrict__ b2, const float* __restrict__ bc1,
               unsigned short* __restrict__ Wft, float* __restrict__ bcf)
{
  __shared__ float wc1s[256 * 32];   // 32 KB
  const int s = blockIdx.x, t = threadIdx.x;
  const float* Wc1s = Wc1 + (size_t)s * 256 * 32;
  #pragma unroll
  for (int i = 0; i < 8; ++i)
    *(float4*)&wc1s[(t + i * 256) * 4] = *(const float4*)&Wc1s[(t + i * 256) * 4];
  __syncthreads();

  const int hh = t >> 1, kb = (t & 1) * 16;
  const float* w2r = W2 + (size_t)s * 128 * 256 + (size_t)hh * 256;
  float acc[16];
  #pragma unroll
  for (int j = 0; j < 16; ++j) acc[j] = 0.f;
  for (int d0 = 0; d0 < 256; d0 += 4) {
    float4 w4 = *(const float4*)(w2r + d0);
    #pragma unroll
    for (int dd = 0; dd < 4; ++dd) {
      float wv = ((const float*)&w4)[dd];
      #pragma unroll
      for (int j = 0; j < 16; ++j)
        acc[j] += wv * wc1s[(d0 + dd) * 32 + kb + j];
    }
  }
  #pragma unroll
  for (int j = 0; j < 16; ++j)
    Wft[((size_t)s * K_N + kb + j) * H_N + hh] = f2bf(acc[j]);

  if (t < K_N) {
    float a = bc1[s * K_N + t];
    for (int d = 0; d < 256; ++d)
      a += b2[s * D_N + d] * wc1s[d * 32 + t];
    bcf[s * K_N + t] = a;
  }
}

// ---------------- fused main kernel ----------------
// grid = 256, block = 512 (8 waves). Per source s (3 barriers):
//   P1: GEMM1(s) col-split (wave w -> h-cols 16w..16w+16) + fold(s-1) -> h_lds
//   barA
//   P2: GEMM3' (ch = relu(h.Wf + bcf)): wave -> (rt3=w>>1, ct3=w&1) tile,
//       shfl-xor 16-lane reduce of relu(ch)*Wc2 -> zp_lds
//   barB
//   P3: GEMM2(s) col-split -> acc2 regs (+b2); tid<64: cw = lam*sigmoid(zp) -> cw_lds
//   barC  (h free for s+1; cw published for fold)
__global__ __launch_bounds__(512, 2)
void lsi_main(const float* __restrict__ x,
              const float* __restrict__ b1,
              const float* __restrict__ b2,
              const float* __restrict__ Wc2,
              const float* __restrict__ bc2,
              const float* __restrict__ lam,
              const unsigned short* __restrict__ W1t,
              const unsigned short* __restrict__ W2t,
              const unsigned short* __restrict__ Wft,
              const float* __restrict__ bcf,
              float* __restrict__ out)
{
  __shared__ unsigned short x_lds[BT * D_N];   // 32 KB, swizzled
  __shared__ unsigned short h_lds[BT * H_N];   // 16 KB, swizzled
  __shared__ float zp_lds[2][BT];
  __shared__ float cw_lds[BT];
  __shared__ float wsum_lds[BT];

  const int tid = threadIdx.x;
  const int w   = tid >> 6;       // wave 0..7
  const int l   = tid & 63;       // lane
  const int rA  = l & 15;
  const int g   = l >> 4;         // k-group 0..3
  const int k8  = g * 8;
  const int b0  = blockIdx.x * BT;
  const int rt3 = w >> 1;         // GEMM3' row tile
  const int ct3 = w & 1;          // GEMM3' col tile

  // ---- stage x tile into LDS as bf16 (swizzled) ----
  {
    int row = tid >> 3;                 // 0..63
    int c0  = (tid & 7) * 32;           // 8 threads per row
    const float* xr = x + (size_t)(b0 + row) * D_N + c0;
    #pragma unroll
    for (int cc = 0; cc < 4; ++cc) {
      float4 f0 = *(const float4*)(xr + cc * 8);
      float4 f1 = *(const float4*)(xr + cc * 8 + 4);
      bf16x8 u;
      u[0] = f2bf(f0.x); u[1] = f2bf(f0.y); u[2] = f2bf(f0.z); u[3] = f2bf(f0.w);
      u[4] = f2bf(f1.x); u[5] = f2bf(f1.y); u[6] = f2bf(f1.z); u[7] = f2bf(f1.w);
      unsigned off = (unsigned)(row * 512 + (c0 + cc * 8) * 2) ^ (unsigned)((row & 7) << 4);
      *(bf16x8*)((char*)x_lds + off) = u;
    }
  }
  if (tid < BT) wsum_lds[tid] = 0.f;

  f32x4 out_acc[2][4];   // [ct][rt] persistent
  f32x4 acc2[2][4];      // [ct][rt] outs(s), folded one source later
  #pragma unroll
  for (int a = 0; a < 2; ++a)
    #pragma unroll
    for (int b = 0; b < 4; ++b)
      out_acc[a][b] = (f32x4){0.f, 0.f, 0.f, 0.f};

  __syncthreads();

  for (int s = 0; s < S_N; ++s) {
    // ---------- P1: GEMM1(s) + fold(s-1) ----------
    f32x4 acc1[4];
    #pragma unroll
    for (int rt = 0; rt < 4; ++rt) acc1[rt] = (f32x4){0.f, 0.f, 0.f, 0.f};
    {
      const unsigned short* B1 = W1t + ((size_t)s * H_N + w * 16 + rA) * D_N + k8;
      #pragma unroll
      for (int ks = 0; ks < 8; ++ks) {
        bf16x8 bfr = *(const bf16x8*)(B1 + ks * 32);
        #pragma unroll
        for (int rt = 0; rt < 4; ++rt) {
          int row = rt * 16 + rA;
          unsigned off = (unsigned)(row * 512 + (ks * 32 + k8) * 2) ^ (unsigned)((row & 7) << 4);
          bf16x8 afr = *(const bf16x8*)((const char*)x_lds + off);
          acc1[rt] = MFMA(afr, bfr, acc1[rt]);
        }
      }
    }
    if (s > 0) {   // fold source s-1 (VALU, overlaps GEMM1 MFMA)
      #pragma unroll
      for (int rt = 0; rt < 4; ++rt) {
        f32x4 c4 = *(const f32x4*)&cw_lds[rt * 16 + g * 4];
        #pragma unroll
        for (int i = 0; i < 4; ++i) {
          out_acc[0][rt][i] += c4[i] * acc2[0][rt][i];
          out_acc[1][rt][i] += c4[i] * acc2[1][rt][i];
        }
      }
    }
    // write h = relu(acc1 + b1) -> LDS (bf16, swizzled)
    {
      const float b1v = b1[s * H_N + w * 16 + rA];
      #pragma unroll
      for (int rt = 0; rt < 4; ++rt)
        #pragma unroll
        for (int i = 0; i < 4; ++i) {
          float v = fmaxf(acc1[rt][i] + b1v, 0.f);
          int row = rt * 16 + g * 4 + i;
          unsigned off = (unsigned)(row * 256 + (w * 16 + rA) * 2) ^ (unsigned)((row & 7) << 4);
          *(unsigned short*)((char*)h_lds + off) = f2bf(v);
        }
    }
    __syncthreads();   // barA: h ready

    // ---------- P2: GEMM3' (h . Wf) + in-wave reduce ----------
    {
      f32x4 acc3 = (f32x4){0.f, 0.f, 0.f, 0.f};
      const unsigned short* Bf = Wft + ((size_t)s * K_N + ct3 * 16 + rA) * H_N + k8;
      #pragma unroll
      for (int ks = 0; ks < 4; ++ks) {
        int row = rt3 * 16 + rA;
        unsigned off = (unsigned)(row * 256 + (ks * 32 + k8) * 2) ^ (unsigned)((row & 7) << 4);
        bf16x8 afr = *(const bf16x8*)((const char*)h_lds + off);
        bf16x8 bfr = *(const bf16x8*)(Bf + ks * 32);
        acc3 = MFMA(afr, bfr, acc3);
      }
      const float bcfv = bcf[s * K_N + ct3 * 16 + rA];
      const float wc2v = Wc2[s * K_N + ct3 * 16 + rA];
      float pz[4];
      #pragma unroll
      for (int i = 0; i < 4; ++i)
        pz[i] = fmaxf(acc3[i] + bcfv, 0.f) * wc2v;
      #pragma unroll
      for (int m = 1; m < 16; m <<= 1)
        #pragma unroll
        for (int i = 0; i < 4; ++i)
          pz[i] += __shfl_xor(pz[i], m);
      if (rA == 0) {
        #pragma unroll
        for (int i = 0; i < 4; ++i)
          zp_lds[ct3][rt3 * 16 + g * 4 + i] = pz[i];
      }
    }
    __syncthreads();   // barB: zp ready

    // ---------- P3: GEMM2(s) -> acc2 ; cw by 64 threads ----------
    #pragma unroll
    for (int a = 0; a < 2; ++a)
      #pragma unroll
      for (int b = 0; b < 4; ++b)
        acc2[a][b] = (f32x4){0.f, 0.f, 0.f, 0.f};
    {
      const unsigned short* B2 = W2t + ((size_t)s * D_N + w * 32 + rA) * H_N + k8;
      #pragma unroll
      for (int ks = 0; ks < 4; ++ks) {
        bf16x8 afr[4];
        #pragma unroll
        for (int rt = 0; rt < 4; ++rt) {
          int row = rt * 16 + rA;
          unsigned off = (unsigned)(row * 256 + (ks * 32 + k8) * 2) ^ (unsigned)((row & 7) << 4);
          afr[rt] = *(const bf16x8*)((const char*)h_lds + off);
        }
        #pragma unroll
        for (int ct = 0; ct < 2; ++ct) {
          bf16x8 bfr = *(const bf16x8*)(B2 + ct * 16 * H_N + ks * 32);
          #pragma unroll
          for (int rt = 0; rt < 4; ++rt)
            acc2[ct][rt] = MFMA(afr[rt], bfr, acc2[ct][rt]);
        }
      }
    }
    {
      float b2v0 = b2[s * D_N + w * 32 + rA];
      float b2v1 = b2[s * D_N + w * 32 + 16 + rA];
      #pragma unroll
      for (int rt = 0; rt < 4; ++rt)
        #pragma unroll
        for (int i = 0; i < 4; ++i) {
          acc2[0][rt][i] += b2v0;
          acc2[1][rt][i] += b2v1;
        }
    }
    if (tid < BT) {
      float z  = zp_lds[0][tid] + zp_lds[1][tid] + bc2[s];
      float cv = lam[s] / (1.f + __expf(-z));
      cw_lds[tid] = cv;
      wsum_lds[tid] += cv;
    }
    __syncthreads();   // barC: h free, cw(s) published
  }

  // ---------- epilogue: fold s=15, normalize, store ----------
  #pragma unroll
  for (int rt = 0; rt < 4; ++rt) {
    f32x4 c4 = *(const f32x4*)&cw_lds[rt * 16 + g * 4];
    #pragma unroll
    for (int i = 0; i < 4; ++i) {
      out_acc[0][rt][i] += c4[i] * acc2[0][rt][i];
      out_acc[1][rt][i] += c4[i] * acc2[1][rt][i];
    }
  }
  #pragma unroll
  for (int rt = 0; rt < 4; ++rt) {
    f32x4 w4 = *(const f32x4*)&wsum_lds[rt * 16 + g * 4];
    #pragma unroll
    for (int i = 0; i < 4; ++i) {
      int row = rt * 16 + g * 4 + i;
      float winv = 1.f / (w4[i] + 1e-6f);
      out[(size_t)(b0 + row) * D_N + w * 32 + rA]      = out_acc[0][rt][i] * winv;
      out[(size_t)(b0 + row) * D_N + w * 32 + 16 + rA] = out_acc[1][rt][i] * winv;
    }
  }
}

extern "C" void kernel_launch(void* const* d_in, const int* in_sizes, int n_in,
                              void* d_out, int out_size, void* d_ws, size_t ws_size,
                              hipStream_t stream) {
  const float* x   = (const float*)d_in[0];
  const float* W1  = (const float*)d_in[1];
  const float* b1  = (const float*)d_in[2];
  const float* W2  = (const float*)d_in[3];
  const float* b2  = (const float*)d_in[4];
  const float* Wc1 = (const float*)d_in[5];
  const float* bc1 = (const float*)d_in[6];
  const float* Wc2 = (const float*)d_in[7];
  const float* bc2 = (const float*)d_in[8];
  const float* lam = (const float*)d_in[9];
  float* out = (float*)d_out;

  // ws: W1t 1MB | W2t 1MB | Wft 128KB | bcf 2KB
  unsigned short* W1t = (unsigned short*)d_ws;
  unsigned short* W2t = W1t + (size_t)S_N * H_N * D_N;
  unsigned short* Wft = W2t + (size_t)S_N * D_N * H_N;
  float*          bcf = (float*)(Wft + (size_t)S_N * K_N * H_N);

  hipLaunchKernelGGL(lsi_transpose, dim3(1024), dim3(256), 0, stream,
                     W1, W2, W1t, W2t);
  hipLaunchKernelGGL(lsi_wfuse, dim3(S_N), dim3(256), 0, stream,
                     W2, Wc1, b2, bc1, Wft, bcf);
  hipLaunchKernelGGL(lsi_main, dim3(16384 / BT), dim3(512), 0, stream,
                     x, b1, b2, Wc2, bc2, lam, W1t, W2t, Wft, bcf, out);
}